// Round 8
// baseline (4052.278 us; speedup 1.0000x reference)
//
#include <hip/hip_runtime.h>
#include <cmath>

// Problem constants: B=256, T=256, D=128, E=32, F1=F2=512
#define B_   256
#define T_   256
#define D_   128
#define E_   32
#define F_   512
#define CB   16             // blocks per cluster
#define RC   16             // rows per cluster
#define ALPHA_F 0.1f
#define SCALE_F 0.31622776601683794f   // sqrt(0.1)
#define WS_FLAGS_BYTES 8192

typedef float f32x4 __attribute__((ext_vector_type(4)));
typedef short s16x8 __attribute__((ext_vector_type(8)));
#define MFMA __builtin_amdgcn_mfma_f32_16x16x32_bf16

// ---- bf16 helpers (RNE) ----
__device__ __forceinline__ unsigned short f2bf(float f) {
    unsigned u = __float_as_uint(f);
    return (unsigned short)((u + 0x7FFFu + ((u >> 16) & 1u)) >> 16);
}
__device__ __forceinline__ unsigned pack2(float lo, float hi) {
    return (unsigned)f2bf(lo) | ((unsigned)f2bf(hi) << 16);
}

// ---- coherent-point primitives (sc0 sc1: write-through stores, L1/L2-bypass loads) ----
__device__ __forceinline__ void st_coh_u32(unsigned* p, unsigned v) {
    __hip_atomic_store(p, v, __ATOMIC_RELAXED, __HIP_MEMORY_SCOPE_AGENT);
}
__device__ __forceinline__ unsigned long long ld_coh_u64(const unsigned long long* p) {
    return __hip_atomic_load(p, __ATOMIC_RELAXED, __HIP_MEMORY_SCOPE_AGENT);
}

// A-fragment (8 bf16) from a frag exchange buffer at the coherent point.
// Layout: u32 index (S*64 + lane)*4 + piece; lane l gets row=l&15, k=32S+8*(l>>4)+e.
__device__ __forceinline__ s16x8 ld_frag(const unsigned* fb, int S, int l) {
    union { unsigned long long q[2]; s16x8 v; } u;
    const unsigned long long* p = (const unsigned long long*)(fb + (unsigned)(S * 64 + l) * 4u);
    u.q[0] = ld_coh_u64(p);
    u.q[1] = ld_coh_u64(p + 1);
    return u.v;
}

// A-fragment from 8 consecutive f32 in global memory (carry / ext paths)
__device__ __forceinline__ s16x8 frag_from_f32(const float* p) {
    float4 a = *(const float4*)p;
    float4 b = *(const float4*)(p + 4);
    union { unsigned q[4]; s16x8 v; } u;
    u.q[0] = pack2(a.x, a.y); u.q[1] = pack2(a.z, a.w);
    u.q[2] = pack2(b.x, b.y); u.q[3] = pack2(b.z, b.w);
    return u.v;
}

// ---- dataflow poll: wait until fl[0..8) all >= want ----
// Producer protocol: data sc0 stores -> s_waitcnt vmcnt(0) -> flag sc0 store.
// Flag observed (sc1) => data is at the coherent point => sc1 data reads fresh.
__device__ __forceinline__ void poll8(const unsigned* fl, unsigned want) {
    for (;;) {
        unsigned long long a = ld_coh_u64((const unsigned long long*)fl);
        unsigned long long b = ld_coh_u64((const unsigned long long*)(fl + 2));
        unsigned long long c = ld_coh_u64((const unsigned long long*)(fl + 4));
        unsigned long long d = ld_coh_u64((const unsigned long long*)(fl + 6));
        unsigned m = (unsigned)a;
        m = min(m, (unsigned)(a >> 32));
        m = min(m, (unsigned)b);  m = min(m, (unsigned)(b >> 32));
        m = min(m, (unsigned)c);  m = min(m, (unsigned)(c >> 32));
        m = min(m, (unsigned)d);  m = min(m, (unsigned)(d >> 32));
        if (m >= want) break;
        __builtin_amdgcn_s_sleep(1);
    }
    asm volatile("" ::: "memory");   // keep data loads after the poll exit
}

__global__ void __launch_bounds__(256, 1)
sde_scan_kernel(const float* __restrict__ carry, const float* __restrict__ x,
                const float* __restrict__ ext,   const float* __restrict__ noise,
                const float* __restrict__ W1,    const float* __restrict__ b1,
                const float* __restrict__ W2,    const float* __restrict__ b2,
                const float* __restrict__ W3,    const float* __restrict__ b3,
                float* __restrict__ out,         void* __restrict__ ws) {
    // Staging scratch for weight->frag conversion (init only) + occupancy pad
    // (94 KB total LDS > 80 KB forces 1 block/CU for an even grid spread).
    __shared__ alignas(16) short stg[43008];      // 84 KB
    __shared__ alignas(16) f32x4 redb[8 * 64];    // 8 KB  K-split partial exchange

    const int tid = threadIdx.x;
    const int bid = blockIdx.x;
    const int cl  = bid & 15;            // cluster
    const int jb  = bid >> 4;            // block-in-cluster 0..15
    const int rb  = cl * RC;             // global batch-row base
    const int cb  = jb * 32;             // block's F1/F2 col base

    const int w  = tid >> 6;             // wave 0..3
    const int l  = tid & 63;
    const int lr = l & 15;               // frag row / col-within-16
    const int lh = l >> 4;               // k-octet / row-quad

    // flags: per cluster 128 u32 (512B): h1fl[32] | h2fl[32] | yfl[8]
    unsigned* fl   = (unsigned*)ws + cl * 128;
    unsigned* h1fl = fl;
    unsigned* h2fl = fl + 32;
    unsigned* yfl  = fl + 64;
    // single-buffered exchanges (WAR-safety proven by flag-dependency chains)
    char* exb = (char*)ws + WS_FLAGS_BYTES;
    unsigned* h1x = (unsigned*)(exb)           + cl * 4096;   // 16 KB/cluster
    unsigned* h2x = (unsigned*)(exb + 262144)  + cl * 4096;   // 16 KB/cluster
    unsigned* yx  = (unsigned*)(exb + 524288)  + cl * 1024;   // 4 KB/cluster

    float* yfin  = out;
    float* ys_o  = out + B_ * D_;
    float* mup_o = ys_o  + (size_t)B_ * T_ * D_;
    float* mus_o = mup_o + (size_t)B_ * T_ * D_;
    float* std_o = mus_o + (size_t)B_ * T_ * D_;

    // ================= init: convert weights to bf16 frags, load to REGISTERS =================
    short* stg1 = stg;            // W1 frags [cg(2)][s(5)][lane][e]
    short* stg2 = stg + 5120;     // W2 frags [cg(2)][s(16)][lane][e]
    for (int e4 = tid; e4 < 160 * 8; e4 += 256) {
        int k = e4 >> 3, c0 = (e4 & 7) << 2;
        float4 v = *(const float4*)(W1 + k * F_ + cb + c0);
        float vv[4] = {v.x, v.y, v.z, v.w};
#pragma unroll
        for (int m = 0; m < 4; m++) {
            int c = c0 + m;
            stg1[((((c >> 4) * 5 + (k >> 5)) * 64) + (c & 15) + 16 * ((k >> 3) & 3)) * 8 + (k & 7)] =
                (short)f2bf(vv[m]);
        }
    }
    for (int e4 = tid; e4 < 512 * 8; e4 += 256) {
        int k = e4 >> 3, c0 = (e4 & 7) << 2;
        float4 v = *(const float4*)(W2 + k * F_ + cb + c0);
        float vv[4] = {v.x, v.y, v.z, v.w};
#pragma unroll
        for (int m = 0; m < 4; m++) {
            int c = c0 + m;
            stg2[((((c >> 4) * 16 + (k >> 5)) * 64) + (c & 15) + 16 * ((k >> 3) & 3)) * 8 + (k & 7)] =
                (short)f2bf(vv[m]);
        }
    }
    __syncthreads();
    s16x8 w1r[5];                 // G1 B-frags (waves 0,1)
    {
        int wg = (w < 2) ? w : 0;
#pragma unroll
        for (int s = 0; s < 5; s++) w1r[s] = *(const s16x8*)&stg1[((wg * 5 + s) * 64 + l) * 8];
    }
    s16x8 w2r0[4], w2r1[4];       // G2 B-frags: cg0/cg1 at ksteps 4w..4w+3
#pragma unroll
    for (int q = 0; q < 4; q++) {
        w2r0[q] = *(const s16x8*)&stg2[((0 * 16 + 4 * w + q) * 64 + l) * 8];
        w2r1[q] = *(const s16x8*)&stg2[((1 * 16 + 4 * w + q) * 64 + l) * 8];
    }
    __syncthreads();
    // W3 slice (32 cols) for owner blocks jb<4: stage then reg-load
    const int c3base = 32 * (jb & 3);
    for (int e4 = tid; e4 < 512 * 8; e4 += 256) {
        int k = e4 >> 3, crel0 = (e4 & 7) << 2;
        float4 v = *(const float4*)(W3 + (size_t)k * D_ + c3base + crel0);
        float vv[4] = {v.x, v.y, v.z, v.w};
#pragma unroll
        for (int m = 0; m < 4; m++) {
            int crel = crel0 + m;
            stg[(((crel >> 4) * 16 + (k >> 5)) * 64 + (crel & 15) + 16 * ((k >> 3) & 3)) * 8 + (k & 7)] =
                (short)f2bf(vv[m]);
        }
    }
    __syncthreads();
    s16x8 w3rA[4], w3rB[4];       // G3 B-frags: col-tiles 0/1 of slice, ksteps 4w..4w+3
#pragma unroll
    for (int q = 0; q < 4; q++) {
        w3rA[q] = *(const s16x8*)&stg[((0 * 16 + 4 * w + q) * 64 + l) * 8];
        w3rB[q] = *(const s16x8*)&stg[((1 * 16 + 4 * w + q) * 64 + l) * 8];
    }

    const int cw = w & 1;                       // bias col-group (valid for w0/w1 roles)
    const float b1r = b1[cb + 16 * cw + lr];
    const float b2r = b2[cb + 16 * cw + lr];
    const int c3 = c3base + 16 * cw + lr;       // owner pointwise column
    const float b3r = b3[c3];
    const bool owner = (jb < 4);

    float y_reg[4];
    if (owner && w < 2) {
#pragma unroll
        for (int i = 0; i < 4; i++) y_reg[i] = carry[(size_t)(rb + 4 * lh + i) * D_ + c3];
    }

    const f32x4 z4 = {0.f, 0.f, 0.f, 0.f};

    for (int t = 0; t < T_; t++) {
        // ============ G1 (waves 0,1): z(160) -> h1 cols [cb+16w, cb+16w+16) ============
        if (w < 2) {
            f32x4 acc = z4;
            if (t == 0) {
#pragma unroll
                for (int s = 0; s < 4; s++) {
                    s16x8 a = frag_from_f32(carry + (size_t)(rb + lr) * D_ + 32 * s + 8 * lh);
                    acc = MFMA(a, w1r[s], acc, 0, 0, 0);
                }
            } else {
                poll8(yfl, (unsigned)t);        // y(t-1) ready (flag value t)
#pragma unroll
                for (int s = 0; s < 4; s++) {
                    s16x8 a = ld_frag(yx, s, l);
                    acc = MFMA(a, w1r[s], acc, 0, 0, 0);
                }
            }
            {
                s16x8 a = frag_from_f32(ext + ((size_t)(rb + lr) * T_ + t) * E_ + 8 * lh);
                acc = MFMA(a, w1r[4], acc, 0, 0, 0);
            }
            const int cl_ = 16 * w + lr;
#pragma unroll
            for (int i = 0; i < 4; i++) {
                float v = tanhf(acc[i] + b1r);
                float pv = __shfl_xor(v, 1);
                if (!(l & 1))
                    st_coh_u32(h1x + (unsigned)(jb * 64 + 4 * lh + i + 16 * (cl_ >> 3)) * 4 + ((cl_ & 7) >> 1),
                               pack2(v, pv));
            }
            asm volatile("s_waitcnt vmcnt(0)" ::: "memory");
            if (l == 0) st_coh_u32(h1fl + jb * 2 + w, (unsigned)(t + 1));
        }

        // ---- owner pointwise prefetch (hides under G2/G3) ----
        float x1p[4], x2p[4], nvp[4];
        if (owner && w < 2) {
#pragma unroll
            for (int i = 0; i < 4; i++) {
                size_t bt = (size_t)(rb + 4 * lh + i) * T_ + t;
                x1p[i] = x[bt * (2 * D_) + c3];
                x2p[i] = x[bt * (2 * D_) + D_ + c3];
                nvp[i] = noise[bt * D_ + c3];
            }
        }

        // ============ G2 (all waves): h1(512) -> h2 cols [cb..cb+32); K-split 4 ways ============
        {
            poll8(h1fl + 8 * w, (unsigned)(t + 1));
            s16x8 a4[4];
#pragma unroll
            for (int q = 0; q < 4; q++) a4[q] = ld_frag(h1x, 4 * w + q, l);
            f32x4 acc0 = z4, acc1 = z4;
#pragma unroll
            for (int q = 0; q < 4; q++) {
                acc0 = MFMA(a4[q], w2r0[q], acc0, 0, 0, 0);
                acc1 = MFMA(a4[q], w2r1[q], acc1, 0, 0, 0);
            }
            // partials: cg0 -> even slots, cg1 -> odd slots (combine-owners keep their own)
            if (w == 0)      { redb[(1 << 6) + l] = acc1; }
            else if (w == 1) { redb[(2 << 6) + l] = acc0; }
            else if (w == 2) { redb[(4 << 6) + l] = acc0; redb[(5 << 6) + l] = acc1; }
            else             { redb[(6 << 6) + l] = acc0; redb[(7 << 6) + l] = acc1; }
            __syncthreads();
            if (w < 2) {
                f32x4 s = (w == 0)
                    ? acc0 + redb[(2 << 6) + l] + redb[(4 << 6) + l] + redb[(6 << 6) + l]
                    : acc1 + redb[(1 << 6) + l] + redb[(5 << 6) + l] + redb[(7 << 6) + l];
                const int cl_ = 16 * w + lr;
#pragma unroll
                for (int i = 0; i < 4; i++) {
                    float v = tanhf(s[i] + b2r);
                    float pv = __shfl_xor(v, 1);
                    if (!(l & 1))
                        st_coh_u32(h2x + (unsigned)(jb * 64 + 4 * lh + i + 16 * (cl_ >> 3)) * 4 + ((cl_ & 7) >> 1),
                                   pack2(v, pv));
                }
                asm volatile("s_waitcnt vmcnt(0)" ::: "memory");
                if (l == 0) st_coh_u32(h2fl + jb * 2 + w, (unsigned)(t + 1));
            }
        }

        // ====== G3 (owner blocks jb<4): h2(512) -> mu_phi cols [32jb..32jb+32); K-split 4 ways ======
        if (owner) {
            __syncthreads();                    // G2 combine-reads of redb done block-wide
            poll8(h2fl + 8 * w, (unsigned)(t + 1));
            s16x8 g3a[4];
#pragma unroll
            for (int q = 0; q < 4; q++) g3a[q] = ld_frag(h2x, 4 * w + q, l);
            f32x4 aA = z4, aB = z4;
#pragma unroll
            for (int q = 0; q < 4; q++) {
                aA = MFMA(g3a[q], w3rA[q], aA, 0, 0, 0);
                aB = MFMA(g3a[q], w3rB[q], aB, 0, 0, 0);
            }
            if (w == 0)      { redb[(1 << 6) + l] = aB; }
            else if (w == 1) { redb[(2 << 6) + l] = aA; }
            else if (w == 2) { redb[(4 << 6) + l] = aA; redb[(5 << 6) + l] = aB; }
            else             { redb[(6 << 6) + l] = aA; redb[(7 << 6) + l] = aB; }
            __syncthreads();
            if (w < 2) {
                f32x4 s = (w == 0)
                    ? aA + redb[(2 << 6) + l] + redb[(4 << 6) + l] + redb[(6 << 6) + l]
                    : aB + redb[(1 << 6) + l] + redb[(5 << 6) + l] + redb[(7 << 6) + l];
                float yn4[4];
#pragma unroll
                for (int i = 0; i < 4; i++) {
                    float mu_phi = s[i] + b3r;
                    int rg = rb + 4 * lh + i;
                    size_t bt = (size_t)rg * T_ + t;
                    float mu = (1.0f - ALPHA_F) * y_reg[i] + ALPHA_F * mu_phi + x1p[i];
                    float xv = x2p[i];
                    float sp = (xv > 0.f) ? (xv + log1pf(expf(-xv))) : log1pf(expf(xv));
                    float sd = SCALE_F * sp;
                    float yn = mu + sd * nvp[i];
                    mup_o[bt * D_ + c3] = mu_phi;
                    mus_o[bt * D_ + c3] = mu;
                    std_o[bt * D_ + c3] = sd;
                    ys_o [bt * D_ + c3] = yn;
                    y_reg[i] = yn;
                    yn4[i] = yn;
                    if (t == T_ - 1) yfin[(size_t)rg * D_ + c3] = yn;
                }
                // y frag exchange: kstep jb, k-index = c3
#pragma unroll
                for (int i = 0; i < 4; i++) {
                    float pv = __shfl_xor(yn4[i], 1);
                    if (!(l & 1))
                        st_coh_u32(yx + (unsigned)(jb * 64 + 4 * lh + i + 16 * ((c3 >> 3) & 3)) * 4 + ((c3 & 7) >> 1),
                                   pack2(yn4[i], pv));
                }
                asm volatile("s_waitcnt vmcnt(0)" ::: "memory");
                if (l == 0) st_coh_u32(yfl + jb * 2 + w, (unsigned)(t + 1));
            }
        }
    }
}

extern "C" void kernel_launch(void* const* d_in, const int* in_sizes, int n_in,
                              void* d_out, int out_size, void* d_ws, size_t ws_size,
                              hipStream_t stream) {
    const float* carry = (const float*)d_in[0];
    const float* x     = (const float*)d_in[1];
    const float* ext   = (const float*)d_in[2];
    const float* noise = (const float*)d_in[3];
    const float* W1    = (const float*)d_in[4];
    const float* b1    = (const float*)d_in[5];
    const float* W2    = (const float*)d_in[6];
    const float* b2    = (const float*)d_in[7];
    const float* W3    = (const float*)d_in[8];
    const float* b3    = (const float*)d_in[9];
    float* out = (float*)d_out;
    void* ws   = d_ws;

    // Zero the flag region each call (flags are monotonic within a call).
    hipMemsetAsync(d_ws, 0, WS_FLAGS_BYTES, stream);

    sde_scan_kernel<<<dim3(256), dim3(256), 0, stream>>>(
        carry, x, ext, noise, W1, b1, W2, b2, W3, b3, out, ws);
}

// Round 9
// 3630.400 us; speedup vs baseline: 1.1162x; 1.1162x over previous
//
#include <hip/hip_runtime.h>
#include <cmath>

// Problem constants: B=256, T=256, D=128, E=32, F1=F2=512
#define B_   256
#define T_   256
#define D_   128
#define E_   32
#define F_   512
#define CB   4              // blocks per cluster
#define RC   16             // rows per cluster
#define ALPHA_F 0.1f
#define SCALE_F 0.31622776601683794f   // sqrt(0.1)
#define WS_SYNC_BYTES 4096

typedef float f32x4 __attribute__((ext_vector_type(4)));
typedef short s16x8 __attribute__((ext_vector_type(8)));
#define MFMA __builtin_amdgcn_mfma_f32_16x16x32_bf16

// ---- bf16 helpers (RNE) ----
__device__ __forceinline__ unsigned short f2bf(float f) {
    unsigned u = __float_as_uint(f);
    return (unsigned short)((u + 0x7FFFu + ((u >> 16) & 1u)) >> 16);
}
__device__ __forceinline__ unsigned pack2(float lo, float hi) {
    return (unsigned)f2bf(lo) | ((unsigned)f2bf(hi) << 16);
}

// ---- coherent-point primitives (sc0 sc1: write-through stores, L1/L2-bypass loads) ----
__device__ __forceinline__ void st_coh_u32(unsigned* p, unsigned v) {
    __hip_atomic_store(p, v, __ATOMIC_RELAXED, __HIP_MEMORY_SCOPE_AGENT);
}
__device__ __forceinline__ unsigned long long ld_coh_u64(const unsigned long long* p) {
    return __hip_atomic_load(p, __ATOMIC_RELAXED, __HIP_MEMORY_SCOPE_AGENT);
}

// A-fragment (8 bf16) from a frag exchange buffer at the coherent point.
// Layout: u32 index (S*64 + lane)*4 + piece; lane l gets row=l&15, k=32S+8*(l>>4)+e.
__device__ __forceinline__ s16x8 ld_frag(const unsigned* fb, int S, int l) {
    union { unsigned long long q[2]; s16x8 v; } u;
    const unsigned long long* p = (const unsigned long long*)(fb + (unsigned)(S * 64 + l) * 4u);
    u.q[0] = ld_coh_u64(p);
    u.q[1] = ld_coh_u64(p + 1);
    return u.v;
}

// A-fragment from 8 consecutive f32 in global memory (carry / ext paths)
__device__ __forceinline__ s16x8 frag_from_f32(const float* p) {
    float4 a = *(const float4*)p;
    float4 b = *(const float4*)(p + 4);
    union { unsigned q[4]; s16x8 v; } u;
    u.q[0] = pack2(a.x, a.y); u.q[1] = pack2(a.z, a.w);
    u.q[2] = pack2(b.x, b.y); u.q[3] = pack2(b.z, b.w);
    return u.v;
}

// ---- 4-block cluster barrier: RMW-free (per-block slot store + min-poll) ----
// Each wave drains its write-through stores (vmcnt 0); block-sync so ALL waves'
// stores are at the coherent point; thread 0 publishes generation g to its own
// slot and polls min(slots) >= g. Monotonic generations, no reset, no atomics.
__device__ __forceinline__ void poll4(const unsigned* fl, unsigned want) {
    for (;;) {
        unsigned long long a = ld_coh_u64((const unsigned long long*)fl);
        unsigned long long b = ld_coh_u64((const unsigned long long*)(fl + 2));
        unsigned m0 = (unsigned)a, m1 = (unsigned)(a >> 32);
        unsigned m2 = (unsigned)b, m3 = (unsigned)(b >> 32);
        unsigned m = m0 < m1 ? m0 : m1;
        unsigned n = m2 < m3 ? m2 : m3;
        m = m < n ? m : n;
        if (m >= want) break;
        __builtin_amdgcn_s_sleep(1);
    }
    asm volatile("" ::: "memory");
}
__device__ __forceinline__ void cluster_barrier(unsigned* flags, int jb, unsigned g) {
    asm volatile("s_waitcnt vmcnt(0)" ::: "memory");
    __syncthreads();
    if (threadIdx.x == 0) {
        st_coh_u32(flags + jb, g);
        poll4(flags, g);
    }
    __syncthreads();
}

__global__ void __launch_bounds__(256, 1)
sde_scan_kernel(const float* __restrict__ carry, const float* __restrict__ x,
                const float* __restrict__ ext,   const float* __restrict__ noise,
                const float* __restrict__ W1,    const float* __restrict__ b1,
                const float* __restrict__ W2,    const float* __restrict__ b2,
                const float* __restrict__ W3,    const float* __restrict__ b3,
                float* __restrict__ out,         void* __restrict__ ws) {
    // W2 slice as bf16 B-frags [tile(8)][s(16)][lane][e] = 128 KB; doubles as
    // init staging for W1/W3 before they move to registers.
    __shared__ alignas(16) short W2f[8 * 16 * 64 * 8];   // 131072 B
    __shared__ alignas(16) short y_lds[4 * 64 * 8];      // 4096 B: y as A-frags [s(4)][lane][e]

    const int tid = threadIdx.x;
    const int bid = blockIdx.x;
    const int cl  = bid & 15;            // cluster (blocks cl, cl+16, cl+32, cl+48)
    const int jb  = bid >> 4;            // block-in-cluster 0..3
    const int rb  = cl * RC;             // global batch-row base

    const int w  = tid >> 6;             // wave 0..3
    const int l  = tid & 63;
    const int lr = l & 15;               // frag row / col-within-16
    const int lh = l >> 4;               // k-octet / row-quad

    unsigned* flags = (unsigned*)ws + cl * 64;                                   // 4 slots, 256B stride
    unsigned* h1x = (unsigned*)((char*)ws + WS_SYNC_BYTES) + cl * 4096;          // 16 KB/cluster
    unsigned* h2x = (unsigned*)((char*)ws + WS_SYNC_BYTES + 262144) + cl * 4096; // 16 KB/cluster

    float* yfin  = out;
    float* ys_o  = out + B_ * D_;
    float* mup_o = ys_o  + (size_t)B_ * T_ * D_;
    float* mus_o = mup_o + (size_t)B_ * T_ * D_;
    float* std_o = mus_o + (size_t)B_ * T_ * D_;

    // ================= init: convert weights to bf16 frags =================
    short* stg = W2f;
    // (a) W1 slice cols [128jb, 128jb+128), K=160 -> [tile(8)][s(5)][lane][e]
    for (int e4 = tid; e4 < 160 * 32; e4 += 256) {
        int k = e4 >> 5, c0 = (e4 & 31) << 2;
        float4 v = *(const float4*)(W1 + (size_t)k * F_ + 128 * jb + c0);
        float vv[4] = {v.x, v.y, v.z, v.w};
#pragma unroll
        for (int m = 0; m < 4; m++) {
            int c = c0 + m;
            stg[(((c >> 4) * 5 + (k >> 5)) * 64 + (c & 15) + 16 * ((k >> 3) & 3)) * 8 + (k & 7)] =
                (short)f2bf(vv[m]);
        }
    }
    __syncthreads();
    s16x8 w1r[2][5];                     // wave w owns tiles {2w, 2w+1}
#pragma unroll
    for (int p = 0; p < 2; p++)
#pragma unroll
        for (int s = 0; s < 5; s++)
            w1r[p][s] = *(const s16x8*)&stg[(((2 * w + p) * 5 + s) * 64 + l) * 8];
    __syncthreads();
    // (b) FULL W3 (128 cols), K=512 -> [tile(8)][s(16)][lane][e] (128 KB staging)
    for (int e4 = tid; e4 < 512 * 32; e4 += 256) {
        int k = e4 >> 5, c0 = (e4 & 31) << 2;
        float4 v = *(const float4*)(W3 + (size_t)k * D_ + c0);
        float vv[4] = {v.x, v.y, v.z, v.w};
#pragma unroll
        for (int m = 0; m < 4; m++) {
            int c = c0 + m;
            stg[(((c >> 4) * 16 + (k >> 5)) * 64 + (c & 15) + 16 * ((k >> 3) & 3)) * 8 + (k & 7)] =
                (short)f2bf(vv[m]);
        }
    }
    __syncthreads();
    s16x8 w3r[2][16];                    // wave w: D-col tiles {2w, 2w+1}, all 16 ksteps
#pragma unroll
    for (int p = 0; p < 2; p++)
#pragma unroll
        for (int q = 0; q < 16; q++)
            w3r[p][q] = *(const s16x8*)&stg[(((2 * w + p) * 16 + q) * 64 + l) * 8];
    __syncthreads();
    // (c) W2 slice cols [128jb, 128jb+128), K=512 -> resident LDS frags
    for (int e4 = tid; e4 < 512 * 32; e4 += 256) {
        int k = e4 >> 5, c0 = (e4 & 31) << 2;
        float4 v = *(const float4*)(W2 + (size_t)k * F_ + 128 * jb + c0);
        float vv[4] = {v.x, v.y, v.z, v.w};
#pragma unroll
        for (int m = 0; m < 4; m++) {
            int c = c0 + m;
            W2f[(((c >> 4) * 16 + (k >> 5)) * 64 + (c & 15) + 16 * ((k >> 3) & 3)) * 8 + (k & 7)] =
                (short)f2bf(vv[m]);
        }
    }
    __syncthreads();

    // biases + carried y state: wave w owns cols {32w+16p+lr} x rows 4lh+i
    float b1r[2], b2r[2], b3r[2];
    float y_reg[2][4];
#pragma unroll
    for (int p = 0; p < 2; p++) {
        int c = 32 * w + 16 * p + lr;
        b1r[p] = b1[128 * jb + c];
        b2r[p] = b2[128 * jb + c];
        b3r[p] = b3[c];
#pragma unroll
        for (int i = 0; i < 4; i++)
            y_reg[p][i] = carry[(size_t)(rb + 4 * lh + i) * D_ + c];
    }

    const f32x4 z4 = {0.f, 0.f, 0.f, 0.f};
    unsigned gbar = 0;

    for (int t = 0; t < T_; t++) {
        // ---- prefetch pointwise inputs (consumed in G3; hidden under G1+G2+barriers) ----
        float x1p[2][4], x2p[2][4], nvp[2][4];
#pragma unroll
        for (int p = 0; p < 2; p++) {
            int c = 32 * w + 16 * p + lr;
#pragma unroll
            for (int i = 0; i < 4; i++) {
                size_t bt = (size_t)(rb + 4 * lh + i) * T_ + t;
                x1p[p][i] = x[bt * (2 * D_) + c];
                x2p[p][i] = x[bt * (2 * D_) + D_ + c];
                nvp[p][i] = noise[bt * D_ + c];
            }
        }

        // ============ G1: z(160) -> h1 cols [128jb+32w, +32); full-K chained, no reduction ============
        {
            f32x4 acc[2] = {z4, z4};
            if (t == 0) {
#pragma unroll
                for (int s = 0; s < 4; s++) {
                    s16x8 a = frag_from_f32(carry + (size_t)(rb + lr) * D_ + 32 * s + 8 * lh);
                    acc[0] = MFMA(a, w1r[0][s], acc[0], 0, 0, 0);
                    acc[1] = MFMA(a, w1r[1][s], acc[1], 0, 0, 0);
                }
            } else {
#pragma unroll
                for (int s = 0; s < 4; s++) {
                    s16x8 a = *(const s16x8*)&y_lds[(s * 64 + l) * 8];
                    acc[0] = MFMA(a, w1r[0][s], acc[0], 0, 0, 0);
                    acc[1] = MFMA(a, w1r[1][s], acc[1], 0, 0, 0);
                }
            }
            {
                s16x8 a = frag_from_f32(ext + ((size_t)(rb + lr) * T_ + t) * E_ + 8 * lh);
                acc[0] = MFMA(a, w1r[0][4], acc[0], 0, 0, 0);
                acc[1] = MFMA(a, w1r[1][4], acc[1], 0, 0, 0);
            }
#pragma unroll
            for (int p = 0; p < 2; p++)
#pragma unroll
                for (int i = 0; i < 4; i++) {
                    float v = tanhf(acc[p][i] + b1r[p]);
                    float pv = __shfl_xor(v, 1);
                    if (!(l & 1))
                        st_coh_u32(h1x + (unsigned)((4 * jb + w) * 64 + 4 * lh + i
                                                    + 16 * (2 * p + (lr >> 3))) * 4 + ((lr & 7) >> 1),
                                   pack2(v, pv));
                }
        }
        cluster_barrier(flags, jb, ++gbar);     // h1 complete cluster-wide

        // ============ G2: h1(512) -> h2 cols [128jb+32w, +32); full-K chained ============
        {
            s16x8 a16[16];
#pragma unroll
            for (int q = 0; q < 16; q++) a16[q] = ld_frag(h1x, q, l);
            f32x4 acc[2] = {z4, z4};
#pragma unroll
            for (int q = 0; q < 16; q++) {
                acc[0] = MFMA(a16[q], *(const s16x8*)&W2f[(((2 * w + 0) * 16 + q) * 64 + l) * 8], acc[0], 0, 0, 0);
                acc[1] = MFMA(a16[q], *(const s16x8*)&W2f[(((2 * w + 1) * 16 + q) * 64 + l) * 8], acc[1], 0, 0, 0);
            }
#pragma unroll
            for (int p = 0; p < 2; p++)
#pragma unroll
                for (int i = 0; i < 4; i++) {
                    float v = tanhf(acc[p][i] + b2r[p]);
                    float pv = __shfl_xor(v, 1);
                    if (!(l & 1))
                        st_coh_u32(h2x + (unsigned)((4 * jb + w) * 64 + 4 * lh + i
                                                    + 16 * (2 * p + (lr >> 3))) * 4 + ((lr & 7) >> 1),
                                   pack2(v, pv));
                }
        }
        cluster_barrier(flags, jb, ++gbar);     // h2 complete cluster-wide

        // ====== G3 (redundant in all 4 blocks): h2(512) -> mu_phi cols [32w, 32w+32) ======
        // Redundancy keeps y block-local (LDS) -> no 3rd barrier. Stores filtered i==jb.
        {
            s16x8 a16[16];
#pragma unroll
            for (int q = 0; q < 16; q++) a16[q] = ld_frag(h2x, q, l);
            f32x4 acc[2] = {z4, z4};
#pragma unroll
            for (int q = 0; q < 16; q++) {
                acc[0] = MFMA(a16[q], w3r[0][q], acc[0], 0, 0, 0);
                acc[1] = MFMA(a16[q], w3r[1][q], acc[1], 0, 0, 0);
            }
#pragma unroll
            for (int p = 0; p < 2; p++) {
                const int c = 32 * w + 16 * p + lr;
#pragma unroll
                for (int i = 0; i < 4; i++) {
                    float mu_phi = acc[p][i] + b3r[p];
                    int rg = rb + 4 * lh + i;
                    size_t bt = (size_t)rg * T_ + t;
                    float mu = (1.0f - ALPHA_F) * y_reg[p][i] + ALPHA_F * mu_phi + x1p[p][i];
                    float xv = x2p[p][i];
                    float sp = (xv > 0.f) ? (xv + log1pf(expf(-xv))) : log1pf(expf(xv));
                    float sd = SCALE_F * sp;
                    float yn = mu + sd * nvp[p][i];
                    if (i == jb) {                      // unique-store ownership by row-quad
                        mup_o[bt * D_ + c] = mu_phi;
                        mus_o[bt * D_ + c] = mu;
                        std_o[bt * D_ + c] = sd;
                        ys_o [bt * D_ + c] = yn;
                        if (t == T_ - 1) yfin[(size_t)rg * D_ + c] = yn;
                    }
                    y_reg[p][i] = yn;
                    y_lds[((unsigned)(w * 64 + 4 * lh + i + 16 * (2 * p + (lr >> 3)))) * 8 + (lr & 7)] =
                        (short)f2bf(yn);
                }
            }
        }
        __syncthreads();                        // y_lds ready for next step's G1
    }
}

extern "C" void kernel_launch(void* const* d_in, const int* in_sizes, int n_in,
                              void* d_out, int out_size, void* d_ws, size_t ws_size,
                              hipStream_t stream) {
    const float* carry = (const float*)d_in[0];
    const float* x     = (const float*)d_in[1];
    const float* ext   = (const float*)d_in[2];
    const float* noise = (const float*)d_in[3];
    const float* W1    = (const float*)d_in[4];
    const float* b1    = (const float*)d_in[5];
    const float* W2    = (const float*)d_in[6];
    const float* b2    = (const float*)d_in[7];
    const float* W3    = (const float*)d_in[8];
    const float* b3    = (const float*)d_in[9];
    float* out = (float*)d_out;
    void* ws   = d_ws;

    // Zero only the barrier flag region (generations are monotonic within a call).
    hipMemsetAsync(d_ws, 0, WS_SYNC_BYTES, stream);

    // 64 blocks: 16 clusters x 4 blocks; cluster = {c, c+16, c+32, c+48} (one XCD under rr).
    sde_scan_kernel<<<dim3(64), dim3(256), 0, stream>>>(
        carry, x, ext, noise, W1, b1, W2, b2, W3, b3, out, ws);
}